// Round 8
// baseline (12.345 us; speedup 1.0000x reference)
//
#include <hip/hip_runtime.h>
#include <math.h>

#define LC   32
#define QC   4096
#define WC   3972
#define XSEG 640            // x floats staged per wave
// skew: +3 pad per 32-float run -> bank stride 35 (==3 mod 32) -> <=2-way
#define SKF(a) ((a) + 3 * ((a) >> 5))
#define XPAD 700            // SKF(639)=696
#define PPAD 560            // SKF(511)=556

__global__ __launch_bounds__(512, 4) void feature_kernel(
    const float* __restrict__ x,          // (B, C, Q)
    const float* __restrict__ shp,        // (L,)
    const float* __restrict__ posMap,     // (W,)
    const float* __restrict__ posSlope_p, // scalar
    float* __restrict__ out,              // (B,)
    int C)
{
    __shared__ float sx[8][XPAD];   // per-wave x segments
    __shared__ float sp[8][PPAD];   // per-wave position weights
    __shared__ float smin[8];

    const int tid  = threadIdx.x;
    const int b    = blockIdx.x;
    const int lane = tid & 63;
    const int v    = tid >> 6;              // wave 0..7
    const int wb   = 496 * v;               // first window owned by this wave
    const int Wlim = (v == 7) ? 500 : 496;  // 7*496+500 == 3972 == WC

    // ---- wave-local staging: x segment [wb, wb+640) (160 float4) ----
    float* sxv = sx[v];
    {
        const float4* xr4 = reinterpret_cast<const float4*>(
            x + ((size_t)b * C + 3) * QC + wb);   // wb*4B is 16B-aligned
        #pragma unroll
        for (int s = 0; s < 3; ++s) {
            int i4 = lane + 64 * s;
            if (i4 < XSEG / 4) {
                // tail of wave 7 reads past row end into channel 4: in-bounds
                // of x, finite garbage, masked by Wlim below.
                float4 w4 = xr4[i4];
                int sk = SKF(4 * i4);       // float4 stays within a 32-run
                sxv[sk] = w4.x; sxv[sk+1] = w4.y; sxv[sk+2] = w4.z; sxv[sk+3] = w4.w;
            }
        }
    }
    // ---- wave-local staging: position weights w(pos)=ps*elu(-pos)+2 ----
    float* spv = sp[v];
    {
        const float ps = posSlope_p[0];
        #pragma unroll
        for (int s = 0; s < 2; ++s) {
            int i4 = lane + 64 * s;         // 0..127
            int g4 = 124 * v + i4;          // global float4 index into posMap
            float4 z;
            if (g4 <= WC / 4 - 1) {         // full in-bounds float4
                z = reinterpret_cast<const float4*>(posMap)[g4];
            } else {                        // only wave 7, last 3 float4s
                int g = 4 * g4;
                z.x = posMap[min(g,     WC - 1)];
                z.y = posMap[min(g + 1, WC - 1)];
                z.z = posMap[min(g + 2, WC - 1)];
                z.w = posMap[min(g + 3, WC - 1)];
            }
            float e0 = (-z.x > 0.f) ? -z.x : (__expf(-z.x) - 1.f);
            float e1 = (-z.y > 0.f) ? -z.y : (__expf(-z.y) - 1.f);
            float e2 = (-z.z > 0.f) ? -z.z : (__expf(-z.z) - 1.f);
            float e3 = (-z.w > 0.f) ? -z.w : (__expf(-z.w) - 1.f);
            int sk = SKF(4 * i4);
            spv[sk]   = fmaf(ps, e0, 2.0f);
            spv[sk+1] = fmaf(ps, e1, 2.0f);
            spv[sk+2] = fmaf(ps, e2, 2.0f);
            spv[sk+3] = fmaf(ps, e3, 2.0f);
        }
    }

    // shapelet (uniform addresses) + moments
    float sreg[LC];
    #pragma unroll
    for (int j = 0; j < LC; ++j) sreg[j] = shp[j];
    float Ssum = 0.f, S2 = 0.f;
    #pragma unroll
    for (int j = 0; j < LC; ++j) { Ssum += sreg[j]; S2 = fmaf(sreg[j], sreg[j], S2); }
    const float C0 = S2 * (1.0f / 32.0f) + 31.0f / 32.0f;

    // No __syncthreads: each wave reads only its own LDS slices.
    // Drain this wave's ds_writes before its ds_reads.
    asm volatile("s_waitcnt lgkmcnt(0)" ::: "memory");

    // lane -> window mapping within the wave: off = r + 32q + 4k
    // (r=lane&3, q=lane>>2, k=0..7) is a bijection onto [0,512)
    const int r   = lane & 3;
    const int q   = lane >> 2;
    const int w0l = r + 32 * q;      // local offset of lane's first window

    // ---- fill rotating register buffer ----
    float buf[32];
    #pragma unroll
    for (int p = 0; p < 32; ++p)
        buf[p] = sxv[SKF(w0l + 4 * p)];

    float a0=0,a1=0,a2=0,a3=0, q0=0,q1=0,q2=0,q3=0;
    #pragma unroll
    for (int p = 0; p < 32; p += 4) {
        a0 += buf[p];   q0 = fmaf(buf[p],   buf[p],   q0);
        a1 += buf[p+1]; q1 = fmaf(buf[p+1], buf[p+1], q1);
        a2 += buf[p+2]; q2 = fmaf(buf[p+2], buf[p+2], q2);
        a3 += buf[p+3]; q3 = fmaf(buf[p+3], buf[p+3], q3);
    }
    float sum = (a0+a1)+(a2+a3);
    float sq  = (q0+q1)+(q2+q3);

    float best = INFINITY;

    #pragma unroll
    for (int k = 0; k < 8; ++k) {
        if (k > 0) {
            int slot = (k + 31) & 31;
            float oldv = buf[slot];
            float newv = sxv[SKF(w0l + 4 * (k + 31))];
            sum += newv - oldv;
            sq  += fmaf(newv, newv, -(oldv * oldv));
            buf[slot] = newv;
        }
        float d0=0,d1=0,d2=0,d3=0;
        #pragma unroll
        for (int j = 0; j < LC; j += 4) {
            d0 = fmaf(sreg[j],   buf[(k+j)   & 31], d0);
            d1 = fmaf(sreg[j+1], buf[(k+j+1) & 31], d1);
            d2 = fmaf(sreg[j+2], buf[(k+j+2) & 31], d2);
            d3 = fmaf(sreg[j+3], buf[(k+j+3) & 31], d3);
        }
        float dot = (d0+d1)+(d2+d3);

        const int  off   = w0l + 4 * k;
        const bool valid = off < Wlim;
        float wvv = spv[SKF(off)];

        float m   = sum * (1.0f / 32.0f);
        float var = (sq - 32.0f * m * m) * (1.0f / 31.0f);
        var = fmaxf(var, 1e-24f);
        float inv = __builtin_amdgcn_rsqf(var);
        float t   = fmaf(-m, Ssum, dot);                 // dot - m*Ssum
        float d   = fmaf(-t * (1.0f / 16.0f), inv, C0);  // collapsed epilogue
        float f   = valid ? d * wvv : INFINITY;
        best = fminf(best, f);
    }

    // ---- block min reduction (single barrier, tiny payload) ----
    #pragma unroll
    for (int off = 32; off > 0; off >>= 1)
        best = fminf(best, __shfl_down(best, off, 64));
    if (lane == 0) smin[v] = best;
    __syncthreads();
    if (tid == 0) {
        float m0 = fminf(fminf(smin[0], smin[1]), fminf(smin[2], smin[3]));
        float m1 = fminf(fminf(smin[4], smin[5]), fminf(smin[6], smin[7]));
        out[b] = fmaxf(fminf(m0, m1), 0.0f);
    }
}

extern "C" void kernel_launch(void* const* d_in, const int* in_sizes, int n_in,
                              void* d_out, int out_size, void* d_ws, size_t ws_size,
                              hipStream_t stream) {
    const float* x        = (const float*)d_in[0];
    const float* shp      = (const float*)d_in[1];
    const float* posMap   = (const float*)d_in[2];
    const float* posSlope = (const float*)d_in[3];
    float* out = (float*)d_out;

    const int C = 8;
    const int B = in_sizes[0] / (C * QC);   // 512

    feature_kernel<<<B, 512, 0, stream>>>(x, shp, posMap, posSlope, out, C);
}